// Round 1
// baseline (513.994 us; speedup 1.0000x reference)
//
#include <hip/hip_runtime.h>
#include <math.h>

// Problem constants (fixed by setup_inputs)
#define BB 256      // batch
#define TT 256      // time steps
#define NQ 1000     // num_q
#define DK 128
#define DV 128
#define CC 32

// ---------------------------------------------------------------------------
// Precompute kernel: for a tile of 32 (b,t) pairs, compute
//   wt = softmax(kt @ Mk)            -> Wo  [pairs][32]
//   et = sigmoid(vt @ e_W + e_b)     -> Eo  [pairs][128]
//   at = tanh  (vt @ a_W + a_b)      -> Ao  [pairs][128]
//   ck = kt @ f_W[128:] + f_b        -> Ko  [pairs][128]
// and write the "true" output (responses[:,1:]).
// Block: 128 threads, 32 pairs. Thread tile: 4 pairs x 8 outputs.
// ---------------------------------------------------------------------------

__device__ __forceinline__ float fast_sigmoid(float x) {
    x = fminf(fmaxf(x, -30.f), 30.f);
    return 1.f / (1.f + __expf(-x));
}
__device__ __forceinline__ float fast_tanh(float x) {
    x = fminf(fmaxf(x, -15.f), 15.f);
    float t = __expf(2.f * x);
    return (t - 1.f) / (t + 1.f);
}

__device__ __forceinline__ void pre_gemm(
    const float* __restrict__ src,   // LDS [32][132]
    const float* __restrict__ Wm,    // global 128x128 row-major
    const float* __restrict__ bias,  // global [128]
    int act,                         // 0 sigmoid, 1 tanh, 2 none
    float* __restrict__ dst,         // global: [(base+p)*128 + d]
    size_t base, int tid)
{
    const int p0 = (tid >> 4) * 4;       // pair group 0..7 -> 4 pairs
    const int d0 = (tid & 15) * 8;       // 8 outputs
    float acc[4][8];
#pragma unroll
    for (int ii = 0; ii < 4; ++ii)
#pragma unroll
        for (int k = 0; k < 8; ++k) acc[ii][k] = 0.f;

    for (int j4 = 0; j4 < 128; j4 += 4) {
        float4 v[4];
#pragma unroll
        for (int ii = 0; ii < 4; ++ii)
            v[ii] = *(const float4*)&src[(p0 + ii) * 132 + j4];
#pragma unroll
        for (int jj = 0; jj < 4; ++jj) {
            float4 w0 = *(const float4*)&Wm[(j4 + jj) * 128 + d0];
            float4 w1 = *(const float4*)&Wm[(j4 + jj) * 128 + d0 + 4];
#pragma unroll
            for (int ii = 0; ii < 4; ++ii) {
                float vv = (jj == 0) ? v[ii].x : (jj == 1) ? v[ii].y
                         : (jj == 2) ? v[ii].z : v[ii].w;
                acc[ii][0] = fmaf(vv, w0.x, acc[ii][0]);
                acc[ii][1] = fmaf(vv, w0.y, acc[ii][1]);
                acc[ii][2] = fmaf(vv, w0.z, acc[ii][2]);
                acc[ii][3] = fmaf(vv, w0.w, acc[ii][3]);
                acc[ii][4] = fmaf(vv, w1.x, acc[ii][4]);
                acc[ii][5] = fmaf(vv, w1.y, acc[ii][5]);
                acc[ii][6] = fmaf(vv, w1.z, acc[ii][6]);
                acc[ii][7] = fmaf(vv, w1.w, acc[ii][7]);
            }
        }
    }
    float4 b0 = *(const float4*)&bias[d0];
    float4 b1 = *(const float4*)&bias[d0 + 4];
    float bb[8] = {b0.x, b0.y, b0.z, b0.w, b1.x, b1.y, b1.z, b1.w};
#pragma unroll
    for (int ii = 0; ii < 4; ++ii) {
        float o[8];
#pragma unroll
        for (int k = 0; k < 8; ++k) {
            float x = acc[ii][k] + bb[k];
            o[k] = (act == 0) ? fast_sigmoid(x) : (act == 1) ? fast_tanh(x) : x;
        }
        float* dp = dst + (base + (size_t)(p0 + ii)) * 128 + d0;
        *(float4*)dp       = make_float4(o[0], o[1], o[2], o[3]);
        *(float4*)(dp + 4) = make_float4(o[4], o[5], o[6], o[7]);
    }
}

__global__ __launch_bounds__(128) void pre_kernel(
    const int* __restrict__ skills, const int* __restrict__ responses,
    const float* __restrict__ k_emb, const float* __restrict__ v_emb,
    const float* __restrict__ Mk, const float* __restrict__ fW,
    const float* __restrict__ fb, const float* __restrict__ eW,
    const float* __restrict__ eb, const float* __restrict__ aW,
    const float* __restrict__ ab,
    float* __restrict__ Wo, float* __restrict__ Eo,
    float* __restrict__ Ao, float* __restrict__ Ko,
    float* __restrict__ outTrue,
    int t0, int Tc)
{
    const int tid = threadIdx.x;
    const size_t base = (size_t)blockIdx.x * 32;   // flat pair index in [0, BB*Tc)

    __shared__ float kt[32 * 132];
    __shared__ float vt[32 * 132];
    __shared__ float lg[32 * 33];
    __shared__ int sIdx[32], qIdx[32];

    if (tid < 32) {
        int flat = (int)base + tid;
        int b = flat / Tc, tcc = flat % Tc;
        int t = t0 + tcc;
        int gi = b * TT + t;
        int s = skills[gi];
        int r = responses[gi];
        int mr = (r > -1) ? r : 0;
        sIdx[tid] = s;
        qIdx[tid] = s + NQ * mr;
        if (t >= 1) outTrue[b * (TT - 1) + (t - 1)] = (float)r;
    }
    __syncthreads();

    // gather kt/vt rows into LDS (conflict-free: lane d -> bank d%32)
    for (int i = 0; i < 32; ++i) {
        kt[i * 132 + tid] = k_emb[(size_t)sIdx[i] * DK + tid];
        vt[i * 132 + tid] = v_emb[(size_t)qIdx[i] * DV + tid];
    }
    __syncthreads();

    // wt logits: thread = (pair p, c-octet)
    {
        const int p = tid >> 2;          // 0..31
        const int c0 = (tid & 3) * 8;    // 0,8,16,24
        float acc[8];
#pragma unroll
        for (int k = 0; k < 8; ++k) acc[k] = 0.f;
        for (int j4 = 0; j4 < 128; j4 += 4) {
            float4 kv = *(const float4*)&kt[p * 132 + j4];
#pragma unroll
            for (int jj = 0; jj < 4; ++jj) {
                float vv = (jj == 0) ? kv.x : (jj == 1) ? kv.y : (jj == 2) ? kv.z : kv.w;
                float4 m0 = *(const float4*)&Mk[(j4 + jj) * CC + c0];
                float4 m1 = *(const float4*)&Mk[(j4 + jj) * CC + c0 + 4];
                acc[0] = fmaf(vv, m0.x, acc[0]);
                acc[1] = fmaf(vv, m0.y, acc[1]);
                acc[2] = fmaf(vv, m0.z, acc[2]);
                acc[3] = fmaf(vv, m0.w, acc[3]);
                acc[4] = fmaf(vv, m1.x, acc[4]);
                acc[5] = fmaf(vv, m1.y, acc[5]);
                acc[6] = fmaf(vv, m1.z, acc[6]);
                acc[7] = fmaf(vv, m1.w, acc[7]);
            }
        }
#pragma unroll
        for (int k = 0; k < 8; ++k) lg[p * 33 + c0 + k] = acc[k];
    }
    __syncthreads();
    if (tid < 32) {
        // softmax over 32 logits for pair tid
        float m = -1e30f;
#pragma unroll
        for (int c = 0; c < CC; ++c) m = fmaxf(m, lg[tid * 33 + c]);
        float ex[CC];
        float sum = 0.f;
#pragma unroll
        for (int c = 0; c < CC; ++c) { ex[c] = __expf(lg[tid * 33 + c] - m); sum += ex[c]; }
        float inv = 1.f / sum;
        float* wp = Wo + (base + tid) * CC;
#pragma unroll
        for (int c = 0; c < CC; c += 4)
            *(float4*)(wp + c) = make_float4(ex[c] * inv, ex[c + 1] * inv,
                                             ex[c + 2] * inv, ex[c + 3] * inv);
    }

    // big GEMMs
    pre_gemm(vt, eW, eb, 0, Eo, base, tid);            // et = sigmoid
    pre_gemm(vt, aW, ab, 1, Ao, base, tid);            // at = tanh
    pre_gemm(kt, fW + 128 * 128, fb, 2, Ko, base, tid); // ck = linear
}

// ---------------------------------------------------------------------------
// Sequential kernel: one block per batch element, 256 threads.
// thread = (h, d): h = upper/lower half of the f_W reduction, d = feature.
// f_W[:128] held in registers (64/thread); Mv duplicated across halves
// (32 regs/thread); 2 barriers per step; next-step operands prefetched.
// ---------------------------------------------------------------------------

struct StepBufs { float4 w[8]; float e, a, ck; };

__device__ __forceinline__ void seq_step(
    int tc, int par, int Tc, int t0, int b,
    const float4* __restrict__ W4b, const float* __restrict__ Eb,
    const float* __restrict__ Ab, const float* __restrict__ Kb,
    StepBufs& cur, StepBufs& nxt,
    float (&Mv)[32], const float (&fw)[64], float pwd, float pbv,
    float* rt_lds, float* part_lds, float* red_lds,
    int d, int h, int tid, float* __restrict__ pred)
{
    // prefetch next step's operands
    int tn = (tc + 1 < Tc) ? tc + 1 : tc;
#pragma unroll
    for (int q = 0; q < 8; ++q) nxt.w[q] = W4b[tn * 8 + q];
    nxt.e = Eb[tn * 128 + d];
    nxt.a = Ab[tn * 128 + d];
    nxt.ck = Kb[tn * 128 + d];

    // rt_d = sum_c wt[c] * Mv[c][d]   (Mv duplicated in both halves)
    float r0 = 0.f, r1 = 0.f, r2 = 0.f, r3 = 0.f;
#pragma unroll
    for (int q = 0; q < 8; ++q) {
        float4 w4 = cur.w[q];
        r0 = fmaf(w4.x, Mv[4 * q + 0], r0);
        r1 = fmaf(w4.y, Mv[4 * q + 1], r1);
        r2 = fmaf(w4.z, Mv[4 * q + 2], r2);
        r3 = fmaf(w4.w, Mv[4 * q + 3], r3);
    }
    if (h == 0) rt_lds[d] = (r0 + r1) + (r2 + r3);
    __syncthreads();   // [A]

    // deferred p of previous step (thread 0)
    if (tid == 0 && tc > 0) {
        float s = red_lds[(par ^ 1) * 2 + 0] + red_lds[(par ^ 1) * 2 + 1] + pbv;
        float p = fast_sigmoid(s);
        int tg = t0 + tc - 1;
        if (tg < TT - 1) pred[b * (TT - 1) + tg] = p;
    }

    // ft partial: sum over this half's 64 rows of f_W (in registers)
    float a0 = 0.f, a1 = 0.f, a2 = 0.f, a3 = 0.f;
    const float4* rt4 = (const float4*)rt_lds;
#pragma unroll
    for (int jj = 0; jj < 16; ++jj) {
        float4 r4 = rt4[h * 16 + jj];
        a0 = fmaf(r4.x, fw[4 * jj + 0], a0);
        a1 = fmaf(r4.y, fw[4 * jj + 1], a1);
        a2 = fmaf(r4.z, fw[4 * jj + 2], a2);
        a3 = fmaf(r4.w, fw[4 * jj + 3], a3);
    }
    part_lds[d * 2 + h] = (a0 + a1) + (a2 + a3);
    __syncthreads();   // [B]

    if (h == 0) {
        float x = part_lds[d * 2 + 0] + part_lds[d * 2 + 1] + cur.ck;
        float ft = fast_tanh(x);
        float v = ft * pwd;
#pragma unroll
        for (int off = 1; off < 64; off <<= 1) v += __shfl_xor(v, off, 64);
        if ((tid & 63) == 0) red_lds[par * 2 + (tid >> 6)] = v;
    }

    // Mv update (thread-local): Mv = Mv*(1 - wt_c*et_d) + wt_c*at_d
    float et = cur.e, at = cur.a;
#pragma unroll
    for (int q = 0; q < 8; ++q) {
        float4 w4 = cur.w[q];
        float wc, u;
        wc = w4.x; u = wc * et; Mv[4*q+0] = fmaf(wc, at, fmaf(-u, Mv[4*q+0], Mv[4*q+0]));
        wc = w4.y; u = wc * et; Mv[4*q+1] = fmaf(wc, at, fmaf(-u, Mv[4*q+1], Mv[4*q+1]));
        wc = w4.z; u = wc * et; Mv[4*q+2] = fmaf(wc, at, fmaf(-u, Mv[4*q+2], Mv[4*q+2]));
        wc = w4.w; u = wc * et; Mv[4*q+3] = fmaf(wc, at, fmaf(-u, Mv[4*q+3], Mv[4*q+3]));
    }
}

__global__ __launch_bounds__(256, 1) void seq_kernel(
    const float* __restrict__ W, const float* __restrict__ E,
    const float* __restrict__ A, const float* __restrict__ CK,
    const float* __restrict__ fW, const float* __restrict__ pW,
    const float* __restrict__ pb, const float* __restrict__ Mv0,
    float* __restrict__ pred, float* __restrict__ MvWS,
    int t0, int Tc, int doInit, int doSave)
{
    const int b = blockIdx.x;
    const int tid = threadIdx.x;
    const int d = tid & 127;
    const int h = tid >> 7;

    __shared__ float rt_lds[128];
    __shared__ float part_lds[128 * 2];
    __shared__ float red_lds[4];

    float fw[64];
#pragma unroll
    for (int j = 0; j < 64; ++j) fw[j] = fW[(h * 64 + j) * 128 + d];
    float pwd = pW[d];
    float pbv = pb[0];

    float Mv[32];
    if (doInit) {
#pragma unroll
        for (int c = 0; c < 32; ++c) Mv[c] = Mv0[c * 128 + d];
    } else {
#pragma unroll
        for (int c = 0; c < 32; ++c) Mv[c] = MvWS[(size_t)b * 4096 + c * 128 + d];
    }

    const float4* W4b = (const float4*)(W + (size_t)b * Tc * CC);
    const float* Eb = E + (size_t)b * Tc * 128;
    const float* Ab = A + (size_t)b * Tc * 128;
    const float* Kb = CK + (size_t)b * Tc * 128;

    StepBufs bufA, bufB;
#pragma unroll
    for (int q = 0; q < 8; ++q) bufA.w[q] = W4b[q];
    bufA.e = Eb[d]; bufA.a = Ab[d]; bufA.ck = Kb[d];

    for (int tc = 0; tc < Tc; tc += 2) {
        seq_step(tc,     0, Tc, t0, b, W4b, Eb, Ab, Kb, bufA, bufB,
                 Mv, fw, pwd, pbv, rt_lds, part_lds, red_lds, d, h, tid, pred);
        seq_step(tc + 1, 1, Tc, t0, b, W4b, Eb, Ab, Kb, bufB, bufA,
                 Mv, fw, pwd, pbv, rt_lds, part_lds, red_lds, d, h, tid, pred);
    }
    __syncthreads();
    if (tid == 0) {
        int par = (Tc - 1) & 1;
        float s = red_lds[par * 2 + 0] + red_lds[par * 2 + 1] + pbv;
        float p = fast_sigmoid(s);
        int tg = t0 + Tc - 1;
        if (tg < TT - 1) pred[b * (TT - 1) + tg] = p;
    }
    if (doSave && h == 0) {
#pragma unroll
        for (int c = 0; c < 32; ++c) MvWS[(size_t)b * 4096 + c * 128 + d] = Mv[c];
    }
}

// ---------------------------------------------------------------------------

extern "C" void kernel_launch(void* const* d_in, const int* in_sizes, int n_in,
                              void* d_out, int out_size, void* d_ws, size_t ws_size,
                              hipStream_t stream) {
    const int*   skills    = (const int*)d_in[0];
    const int*   responses = (const int*)d_in[1];
    const float* k_emb     = (const float*)d_in[2];
    const float* v_emb     = (const float*)d_in[3];
    const float* Mk        = (const float*)d_in[4];
    const float* Mv0       = (const float*)d_in[5];
    const float* f_W       = (const float*)d_in[6];
    const float* f_b       = (const float*)d_in[7];
    const float* p_W       = (const float*)d_in[8];
    const float* p_b       = (const float*)d_in[9];
    const float* e_W       = (const float*)d_in[10];
    const float* e_b       = (const float*)d_in[11];
    const float* a_W       = (const float*)d_in[12];
    const float* a_b       = (const float*)d_in[13];

    float* pred    = (float*)d_out;                 // [256][255]
    float* outTrue = pred + BB * (TT - 1);          // [256][255]

    // choose time-chunk so scratch fits ws
    int Tc = TT;
    for (;;) {
        size_t need = (size_t)BB * Tc * (CC + 3 * 128) * sizeof(float);
        if (Tc < TT) need += (size_t)BB * 4096 * sizeof(float);
        if (need <= ws_size || Tc <= 32) break;
        Tc >>= 1;
    }

    float* Wo   = (float*)d_ws;
    float* Eo   = Wo + (size_t)BB * Tc * CC;
    float* Ao   = Eo + (size_t)BB * Tc * 128;
    float* Ko   = Ao + (size_t)BB * Tc * 128;
    float* MvWS = Ko + (size_t)BB * Tc * 128;

    for (int t0 = 0; t0 < TT; t0 += Tc) {
        pre_kernel<<<(BB * Tc) / 32, 128, 0, stream>>>(
            skills, responses, k_emb, v_emb, Mk, f_W, f_b, e_W, e_b, a_W, a_b,
            Wo, Eo, Ao, Ko, outTrue, t0, Tc);
        seq_kernel<<<BB, 256, 0, stream>>>(
            Wo, Eo, Ao, Ko, f_W, p_W, p_b, Mv0,
            pred, MvWS, t0, Tc, t0 == 0 ? 1 : 0, (t0 + Tc < TT) ? 1 : 0);
    }
}